// Round 12
// baseline (456.022 us; speedup 1.0000x reference)
//
#include <hip/hip_runtime.h>

// Problem constants (from reference setup_inputs)
#define N_NODES  200000
#define N_EDGES  6400000
#define NGRAPH   128
#define H        32

// Bucketing parameters
#define BNODES   256        // dst nodes per bucket (8 bits)
#define NBUCK    782        // ceil(200000/256); last bucket: 64 valid nodes
#define P_BLOCKS 256        // partition blocks
#define EPB      25000      // edges per partition block (256*25000 = 6.4M)
#define SORT_CAP 8960       // bucket capacity: mean 8192 + 8.5 sigma (fits, R6-R11)

// MEASURED COST MODEL (R1-R11):
//  - LDS lane-atomics: ~4 cyc/lane, serialized per CU (R5: 204.8M -> 1.35ms;
//    ppart 2/edge -> 83us floor; measured 114).
//  - Global same-address atomics: ~125 cyc chain-serialized per address,
//    parallel across addresses (R6 probe; 256-deep reservation chains OK).
//  - k_bsort_aggr: max(sort atomics 83us, 315MB gather @ ~2.9TB/s ~= 108us)
//    -> 114us measured. Both edge kernels AT their floors.
//  - Encoder spill saga (R7/R8/R10/R11): 1-thread-per-node needs ~100+ live
//    floats; allocator pins VGPR=52 and spills (~70MB scratch WRITE) across
//    ALL source formulations tried, incl. launch_bounds and kernel split.
//    Fix here: 4-LANES-PER-NODE channel-split -> live set structurally <60
//    floats; full-vector deps via __shfl within the 4-lane group.
//  - R10: in-order block dispatch defeats role-fusion overlap -> keep
//    enc / ppart / aggr as separate dispatches.

typedef unsigned short ushort_t;

__device__ __forceinline__ ushort_t f32_to_bf16_rne(float f) {
    unsigned u = __float_as_uint(f);
    unsigned r = (u + 0x7fffu + ((u >> 16) & 1u)) >> 16;
    return (ushort_t)r;
}
__device__ __forceinline__ unsigned pack_bf16x2(float lo, float hi) {
    return (unsigned)f32_to_bf16_rne(lo) | ((unsigned)f32_to_bf16_rne(hi) << 16);
}
__device__ __forceinline__ float bf16_to_f32(ushort_t h) {
    return __uint_as_float(((unsigned)h) << 16);
}

// ---------------------------------------------------------------------------
// K-enc4: encoder with 4 LANES PER NODE (lane r owns output channels
// 8r..8r+7). 200000 nodes = 3125 blocks x 64 nodes exactly (no tail, no
// guards). Per lane: ~1472 FMA + ~112 __shfl. Peak live ~57 floats ->
// no spill possible (the R7-R11 spill was 1-thread-per-node needing 100+).
// Cross-lane data (full xv for hl; full hl/hg for mix; full h0 for heads)
// comes from __shfl within the aligned 4-lane group. All weight slices are
// lane-dependent 32B loads -> L1-resident (23.5KB total), wave-broadcast.
// Outputs perfectly coalesced: group writes contiguous 64B (mb) / 128B (s).
// ---------------------------------------------------------------------------
__global__ __launch_bounds__(256) void k_enc4(
        const float* __restrict__ xl,
        const int*   __restrict__ batch,
        const float* __restrict__ xg,   const float* __restrict__ Wg,
        const float* __restrict__ bg,
        const float* __restrict__ Wl,   const float* __restrict__ bl,
        const float* __restrict__ Wmix, const float* __restrict__ bmix,
        const float* __restrict__ Wmsg, const float* __restrict__ bmsg,
        const float* __restrict__ Wself,const float* __restrict__ bself,
        ushort_t* __restrict__ mb, float* __restrict__ s) {
    int tid   = threadIdx.x;
    int r     = tid & 3;                       // sub-lane in node group
    int n     = blockIdx.x * 64 + (tid >> 2);  // node id (exact fit)
    int lane  = tid & 63;
    int gbase = lane & 60;                     // first lane of this group
    int ch0   = 8 * r;                         // this lane's channel base

    // Coalesced xl row: lane r holds xv[4r..4r+4); rest via shfl.
    float4 xq = ((const float4*)(xl + (size_t)n * 16))[r];

    // xg row (32B) whole per lane — xg is 16KB total, L1/L2-resident.
    float gvv[8];
    {
        int gb = batch[n];
        const float4* q = (const float4*)(xg + (size_t)gb * 8);
        float4 a = q[0], b = q[1];
        gvv[0]=a.x; gvv[1]=a.y; gvv[2]=a.z; gvv[3]=a.w;
        gvv[4]=b.x; gvv[5]=b.y; gvv[6]=b.z; gvv[7]=b.w;
    }

    // ---- hl slice: hlr[i] = relu(bl[ch0+i] + sum_j xv[j]*Wl[j][ch0+i]) ----
    float hlr[8];
    {
        float4 b0 = *(const float4*)(bl + ch0);
        float4 b1 = *(const float4*)(bl + ch0 + 4);
        hlr[0]=b0.x; hlr[1]=b0.y; hlr[2]=b0.z; hlr[3]=b0.w;
        hlr[4]=b1.x; hlr[5]=b1.y; hlr[6]=b1.z; hlr[7]=b1.w;
#pragma unroll
        for (int j = 0; j < 16; ++j) {
            float xvj = __shfl(((const float*)&xq)[j & 3], gbase | (j >> 2), 64);
            float4 w0 = *(const float4*)(Wl + j * H + ch0);
            float4 w1 = *(const float4*)(Wl + j * H + ch0 + 4);
            hlr[0] = fmaf(xvj, w0.x, hlr[0]); hlr[1] = fmaf(xvj, w0.y, hlr[1]);
            hlr[2] = fmaf(xvj, w0.z, hlr[2]); hlr[3] = fmaf(xvj, w0.w, hlr[3]);
            hlr[4] = fmaf(xvj, w1.x, hlr[4]); hlr[5] = fmaf(xvj, w1.y, hlr[5]);
            hlr[6] = fmaf(xvj, w1.z, hlr[6]); hlr[7] = fmaf(xvj, w1.w, hlr[7]);
        }
#pragma unroll
        for (int i = 0; i < 8; ++i) hlr[i] = fmaxf(hlr[i], 0.f);
    }

    // ---- hg slice ----
    float hgr[8];
    {
        float4 b0 = *(const float4*)(bg + ch0);
        float4 b1 = *(const float4*)(bg + ch0 + 4);
        hgr[0]=b0.x; hgr[1]=b0.y; hgr[2]=b0.z; hgr[3]=b0.w;
        hgr[4]=b1.x; hgr[5]=b1.y; hgr[6]=b1.z; hgr[7]=b1.w;
#pragma unroll
        for (int j = 0; j < 8; ++j) {
            float gj = gvv[j];
            float4 w0 = *(const float4*)(Wg + j * H + ch0);
            float4 w1 = *(const float4*)(Wg + j * H + ch0 + 4);
            hgr[0] = fmaf(gj, w0.x, hgr[0]); hgr[1] = fmaf(gj, w0.y, hgr[1]);
            hgr[2] = fmaf(gj, w0.z, hgr[2]); hgr[3] = fmaf(gj, w0.w, hgr[3]);
            hgr[4] = fmaf(gj, w1.x, hgr[4]); hgr[5] = fmaf(gj, w1.y, hgr[5]);
            hgr[6] = fmaf(gj, w1.z, hgr[6]); hgr[7] = fmaf(gj, w1.w, hgr[7]);
        }
#pragma unroll
        for (int i = 0; i < 8; ++i) hgr[i] = fmaxf(hgr[i], 0.f);
    }

    // ---- mix: acc[i] = bmix + sum_k hl_k*W1[k] + hg_k*W2[k] + hi_k*W3[k] ----
    float acc[8];
    {
        float4 b0 = *(const float4*)(bmix + ch0);
        float4 b1 = *(const float4*)(bmix + ch0 + 4);
        acc[0]=b0.x; acc[1]=b0.y; acc[2]=b0.z; acc[3]=b0.w;
        acc[4]=b1.x; acc[5]=b1.y; acc[6]=b1.z; acc[7]=b1.w;
    }
#pragma unroll
    for (int k = 0; k < 32; ++k) {
        int owner = gbase | (k >> 3);
        float hlk = __shfl(hlr[k & 7], owner, 64);
        float hgk = __shfl(hgr[k & 7], owner, 64);
        float hik = hlk * hgk;
        float4 w1a = *(const float4*)(Wmix + k * H + ch0);
        float4 w1b = *(const float4*)(Wmix + k * H + ch0 + 4);
        float4 w2a = *(const float4*)(Wmix + (32 + k) * H + ch0);
        float4 w2b = *(const float4*)(Wmix + (32 + k) * H + ch0 + 4);
        float4 w3a = *(const float4*)(Wmix + (64 + k) * H + ch0);
        float4 w3b = *(const float4*)(Wmix + (64 + k) * H + ch0 + 4);
        acc[0] = fmaf(hlk, w1a.x, fmaf(hgk, w2a.x, fmaf(hik, w3a.x, acc[0])));
        acc[1] = fmaf(hlk, w1a.y, fmaf(hgk, w2a.y, fmaf(hik, w3a.y, acc[1])));
        acc[2] = fmaf(hlk, w1a.z, fmaf(hgk, w2a.z, fmaf(hik, w3a.z, acc[2])));
        acc[3] = fmaf(hlk, w1a.w, fmaf(hgk, w2a.w, fmaf(hik, w3a.w, acc[3])));
        acc[4] = fmaf(hlk, w1b.x, fmaf(hgk, w2b.x, fmaf(hik, w3b.x, acc[4])));
        acc[5] = fmaf(hlk, w1b.y, fmaf(hgk, w2b.y, fmaf(hik, w3b.y, acc[5])));
        acc[6] = fmaf(hlk, w1b.z, fmaf(hgk, w2b.z, fmaf(hik, w3b.z, acc[6])));
        acc[7] = fmaf(hlk, w1b.w, fmaf(hgk, w2b.w, fmaf(hik, w3b.w, acc[7])));
    }
    float h0r[8];
#pragma unroll
    for (int i = 0; i < 8; ++i) h0r[i] = fmaxf(acc[i], 0.f);

    // ---- heads: am = bmsg + h0@Wmsg ; as = bself + h0@Wself (one k loop) ----
    float am[8], as[8];
    {
        float4 m0 = *(const float4*)(bmsg + ch0);
        float4 m1 = *(const float4*)(bmsg + ch0 + 4);
        am[0]=m0.x; am[1]=m0.y; am[2]=m0.z; am[3]=m0.w;
        am[4]=m1.x; am[5]=m1.y; am[6]=m1.z; am[7]=m1.w;
        float4 s0 = *(const float4*)(bself + ch0);
        float4 s1 = *(const float4*)(bself + ch0 + 4);
        as[0]=s0.x; as[1]=s0.y; as[2]=s0.z; as[3]=s0.w;
        as[4]=s1.x; as[5]=s1.y; as[6]=s1.z; as[7]=s1.w;
    }
#pragma unroll
    for (int k = 0; k < 32; ++k) {
        float h0k = __shfl(h0r[k & 7], gbase | (k >> 3), 64);
        float4 wma = *(const float4*)(Wmsg + k * H + ch0);
        float4 wmb = *(const float4*)(Wmsg + k * H + ch0 + 4);
        float4 wsa = *(const float4*)(Wself + k * H + ch0);
        float4 wsb = *(const float4*)(Wself + k * H + ch0 + 4);
        am[0] = fmaf(h0k, wma.x, am[0]); am[1] = fmaf(h0k, wma.y, am[1]);
        am[2] = fmaf(h0k, wma.z, am[2]); am[3] = fmaf(h0k, wma.w, am[3]);
        am[4] = fmaf(h0k, wmb.x, am[4]); am[5] = fmaf(h0k, wmb.y, am[5]);
        am[6] = fmaf(h0k, wmb.z, am[6]); am[7] = fmaf(h0k, wmb.w, am[7]);
        as[0] = fmaf(h0k, wsa.x, as[0]); as[1] = fmaf(h0k, wsa.y, as[1]);
        as[2] = fmaf(h0k, wsa.z, as[2]); as[3] = fmaf(h0k, wsa.w, as[3]);
        as[4] = fmaf(h0k, wsb.x, as[4]); as[5] = fmaf(h0k, wsb.y, as[5]);
        as[6] = fmaf(h0k, wsb.z, as[6]); as[7] = fmaf(h0k, wsb.w, as[7]);
    }

    // ---- coalesced outputs: group writes contiguous 64B (mb) / 128B (s) ----
    uint4 d;
    d.x = pack_bf16x2(fmaxf(am[0], 0.f), fmaxf(am[1], 0.f));
    d.y = pack_bf16x2(fmaxf(am[2], 0.f), fmaxf(am[3], 0.f));
    d.z = pack_bf16x2(fmaxf(am[4], 0.f), fmaxf(am[5], 0.f));
    d.w = pack_bf16x2(fmaxf(am[6], 0.f), fmaxf(am[7], 0.f));
    ((uint4*)(mb + (size_t)n * H))[r] = d;

    float4 sv0, sv1;
    sv0.x = as[0]; sv0.y = as[1]; sv0.z = as[2]; sv0.w = as[3];
    sv1.x = as[4]; sv1.y = as[5]; sv1.z = as[6]; sv1.w = as[7];
    ((float4*)(s + (size_t)n * H))[2 * r]     = sv0;
    ((float4*)(s + (size_t)n * H))[2 * r + 1] = sv1;
}

// ---------------------------------------------------------------------------
// K-ppart: SINGLE-PASS partition (proven 114us, R8/R11). Per block of EPB
// edges: LDS histogram (1 lane-atomic/edge) -> per-(block,bucket) global
// reservation (256-deep chains) -> scatter (1 lane-atomic/edge).
// ---------------------------------------------------------------------------
__global__ __launch_bounds__(1024) void k_ppart(
        const int* __restrict__ ei,
        int* __restrict__ gcur,              // stride 32 ints (128B line pad), pre-zeroed
        unsigned int* __restrict__ ebuf) {   // NBUCK * SORT_CAP
    __shared__ int cnt[NBUCK];
    __shared__ int basex[NBUCK];             // reservation base, then live cursor
    int t = threadIdx.x, blk = blockIdx.x;
    for (int i = t; i < NBUCK; i += 1024) cnt[i] = 0;
    __syncthreads();

    int e0 = blk * EPB, e1 = e0 + EPB;
    for (int e = e0 + t; e < e1; e += 1024)
        atomicAdd(&cnt[ei[N_EDGES + e] >> 8], 1);
    __syncthreads();

    for (int i = t; i < NBUCK; i += 1024) {
        int c = cnt[i];
        basex[i] = (c > 0) ? atomicAdd(&gcur[i * 32], c) : 0;
    }
    __syncthreads();

    for (int e = e0 + t; e < e1; e += 1024) {
        unsigned src = (unsigned)ei[e];           // < 2^18
        int dst = ei[N_EDGES + e];
        int bkt = dst >> 8;
        int pos = atomicAdd(&basex[bkt], 1);
        if (pos < SORT_CAP)                       // belt-and-suspenders
            ebuf[(size_t)bkt * SORT_CAP + pos] = (src << 8) | (unsigned)(dst & 255);
    }
}

// ---------------------------------------------------------------------------
// K-bsort-aggr: FUSED counting-sort + aggregation + output head (proven
// 114us, R8/R11). One block per bucket. SORT_CAP 8960 => LDS 38.9 KB;
// 2-barrier shfl wave scan; INT LDS-atomic sort (2 lane-atomics/edge);
// register-accumulated aggregation with dword gathers (2 bf16 cols/lane,
// 16 lanes/edge). Epilogue verified R1-R11.
// ---------------------------------------------------------------------------
__global__ __launch_bounds__(512, 8) void k_bsort_aggr(
        const int* __restrict__ gcur,        // per-bucket counts (stride 32)
        const unsigned int* __restrict__ ebuf,
        const ushort_t* __restrict__ mb, const float* __restrict__ s,
        const float* __restrict__ Wout, const float* __restrict__ bout,
        float* __restrict__ out) {
    __shared__ unsigned sorted[SORT_CAP];   // 35 KB
    __shared__ int cnt[BNODES];
    __shared__ int offx[BNODES + 1];        // exclusive offsets, offx[256]=size
    __shared__ int cur[BNODES];
    __shared__ int wsum[4];
    int tid = threadIdx.x, b = blockIdx.x;

    size_t base = (size_t)b * SORT_CAP;
    int sz = min(gcur[b * 32], SORT_CAP);

    if (tid < BNODES) cnt[tid] = 0;
    __syncthreads();

    // histogram: 1 int LDS lane-atomic per edge
    for (int j = tid; j < sz; j += 512)
        atomicAdd(&cnt[ebuf[base + j] & 255], 1);
    __syncthreads();

    // 2-barrier shfl scan over 256 counts
    {
        int lane = tid & 63, w = tid >> 6;
        int v = (tid < BNODES) ? cnt[tid] : 0;
#pragma unroll
        for (int d = 1; d < 64; d <<= 1) {
            int u = __shfl_up(v, d, 64);    // harmless for waves 4-7
            if (lane >= d) v += u;
        }
        if (tid < BNODES && lane == 63) wsum[w] = v;
        __syncthreads();
        if (tid < BNODES) {
            int add = 0;
#pragma unroll
            for (int i = 0; i < 3; ++i) add += (i < w) ? wsum[i] : 0;
            int inc = v + add;              // inclusive scan of cnt
            offx[tid + 1] = inc;
            cur[tid] = inc - cnt[tid];      // exclusive (scatter cursor)
            if (tid == 0) offx[0] = 0;
        }
        __syncthreads();
    }

    // scatter into sorted[]: 1 int LDS lane-atomic per edge
    for (int j = tid; j < sz; j += 512) {
        unsigned pk = ebuf[base + j];
        int pos = atomicAdd(&cur[pk & 255], 1);
        sorted[pos] = pk;
    }
    __syncthreads();

    // ---- fused aggregation + output head (register accumulation) ----
    const unsigned* mb32 = (const unsigned*)mb;
    int g = tid >> 4;          // 16-lane group id, 0..31
    int t = tid & 15;          // lane in group; owns columns {2t, 2t+1}

    for (int q = 0; q < 8; ++q) {
        int loc = (g << 3) + q;            // 32 groups x 8 nodes = 256
        int n = b * BNODES + loc;
        int rs = offx[loc];
        int re = offx[loc + 1];
        float a0 = 0.f, a1 = 0.f;

        for (int j = rs; j < re; j += 8) {
            unsigned pk[8], u[8];
#pragma unroll
            for (int k = 0; k < 8; ++k)
                pk[k] = sorted[min(j + k, re - 1)];       // broadcast LDS read
#pragma unroll
            for (int k = 0; k < 8; ++k)
                u[k] = mb32[(pk[k] >> 8) * 16u + (unsigned)t];  // 2 bf16 cols
#pragma unroll
            for (int k = 0; k < 8; ++k) {
                bool ok = (j + k < re);
                a0 += ok ? __uint_as_float(u[k] << 16)         : 0.f;
                a1 += ok ? __uint_as_float(u[k] & 0xffff0000u) : 0.f;
            }
        }

        if (n < N_NODES) {
            // self-loop message + self path, relu, output head
            unsigned u = mb32[(unsigned)n * 16u + (unsigned)t];
            float2 sv = *(const float2*)(s + (size_t)n * H + 2 * t);
            float h0 = fmaxf(a0 + __uint_as_float(u << 16)         + sv.x, 0.f);
            float h1 = fmaxf(a1 + __uint_as_float(u & 0xffff0000u) + sv.y, 0.f);
            float4 w = *(const float4*)(Wout + 4 * t);   // rows {2t,2t+1} of [32][2]
            float p0 = h0 * w.x + h1 * w.z;
            float p1 = h0 * w.y + h1 * w.w;
#pragma unroll
            for (int o = 8; o >= 1; o >>= 1) {
                p0 += __shfl_down(p0, o, 16);
                p1 += __shfl_down(p1, o, 16);
            }
            if (t == 0) {
                float2 o2;
                o2.x = p0 + bout[0];
                o2.y = p1 + bout[1];
                *(float2*)(out + (size_t)n * 2) = o2;
            }
        }
    }
}

// ---------------------------------------------------------------------------
extern "C" void kernel_launch(void* const* d_in, const int* in_sizes, int n_in,
                              void* d_out, int out_size, void* d_ws, size_t ws_size,
                              hipStream_t stream) {
    const float* xl    = (const float*)d_in[0];
    const float* xg    = (const float*)d_in[1];
    const int*   batch = (const int*)  d_in[2];
    const int*   ei    = (const int*)  d_in[3];
    const float* Wl    = (const float*)d_in[4];
    const float* bl    = (const float*)d_in[5];
    const float* Wg    = (const float*)d_in[6];
    const float* bg    = (const float*)d_in[7];
    const float* Wmix  = (const float*)d_in[8];
    const float* bmix  = (const float*)d_in[9];
    const float* Wmsg  = (const float*)d_in[10];
    const float* bmsg  = (const float*)d_in[11];
    const float* Wself = (const float*)d_in[12];
    const float* bself = (const float*)d_in[13];
    const float* Wout  = (const float*)d_in[14];
    const float* bout  = (const float*)d_in[15];
    float* out = (float*)d_out;

    // Workspace layout (66.5 MB total — proven available R6-R11):
    //   s    [N*32]           f32   25.6 MB
    //   mb   [N*32]           u16   12.8 MB
    //   gcur [NBUCK*32]       i32   100 KB  (128B-line-padded cursors)
    //   ebuf [NBUCK*SORT_CAP] u32   28.0 MB (fixed-cap bucket regions)
    float*    s    = (float*)d_ws;
    ushort_t* mb   = (ushort_t*)(s + (size_t)N_NODES * H);
    int*      gcur = (int*)(mb + (size_t)N_NODES * H);
    unsigned int* ebuf = (unsigned int*)(gcur + (size_t)NBUCK * 32);

    hipMemsetAsync(gcur, 0, (size_t)NBUCK * 32 * sizeof(int), stream);

    k_enc4<<<N_NODES / 64, 256, 0, stream>>>(
        xl, batch, xg, Wg, bg, Wl, bl, Wmix, bmix,
        Wmsg, bmsg, Wself, bself, mb, s);

    k_ppart<<<P_BLOCKS, 1024, 0, stream>>>(ei, gcur, ebuf);
    k_bsort_aggr<<<NBUCK, 512, 0, stream>>>(gcur, ebuf, mb, s, Wout, bout, out);
}

// Round 13
// 391.753 us; speedup vs baseline: 1.1641x; 1.1641x over previous
//
#include <hip/hip_runtime.h>

// Problem constants (from reference setup_inputs)
#define N_NODES  200000
#define N_EDGES  6400000
#define NGRAPH   128
#define H        32

// Bucketing parameters
#define BNODES   256        // dst nodes per bucket (8 bits)
#define NBUCK    782        // ceil(200000/256); last bucket: 64 valid nodes
#define P_BLOCKS 256        // partition-role blocks (fused grid blocks 0..255)
#define EPB      25000      // edges per partition block (256*25000 = 6.4M)
#define ENC_BLOCKS 782      // encoder-role blocks (fused grid blocks 256..1037)
#define SORT_CAP 8960       // bucket capacity: mean 8192 + 8.5 sigma (fits, R6-R12)

// MEASURED COST MODEL (R1-R12):
//  - LDS lane-atomics: ~4 cyc/lane, serialized per CU (ppart 2/edge -> 83us
//    floor, measured 114; R5 f32-scatter 32/edge -> 1.35ms).
//  - Global same-address atomics: ~125 cyc chain-serialized per address
//    (R6 probe); 256-deep reservation chains ~13us.
//  - k_bsort_aggr: max(sort atomics 83us, 315MB gather) -> 114us. At floor.
//  - ENCODER (R7/R11/R12 triangulation): ~110-150us in EVERY formulation.
//    R12 enc4 had ZERO spill (WRITE 37.5MB ideal) yet ran 151us, VALU 20%
//    -> the cost is OPERAND-DELIVERY LATENCY at ~12 waves/CU (grid-limited),
//    not spill. s_load latency (R7/R11) and divergent VMEM (R12) both stall.
//  - R10: role-fusion failed because enc blocks (0..781) drained before
//    ppart blocks started (in-order dispatch). FIX HERE: ppart = blocks
//    0..255, enc = 256..1037; whole grid co-resident (8 blocks/CU capacity)
//    -> enc's VALU work fills ppart's atomic-stall cycles on every CU.

typedef unsigned short ushort_t;

__device__ __forceinline__ ushort_t f32_to_bf16_rne(float f) {
    unsigned u = __float_as_uint(f);
    unsigned r = (u + 0x7fffu + ((u >> 16) & 1u)) >> 16;
    return (ushort_t)r;
}
__device__ __forceinline__ float bf16_to_f32(ushort_t h) {
    return __uint_as_float(((unsigned)h) << 16);
}

// ---------------------------------------------------------------------------
// K-part-enc: FUSED partition + encoder, partition FIRST in blockIdx order.
// Blocks [0, P_BLOCKS): partition role (3 phases, proven R8/R11 logic at
//   256 threads): LDS histogram (1 lane-atomic/edge) -> per-(block,bucket)
//   global reservation (256-deep chains) -> scatter (1 lane-atomic/edge).
// Blocks [P_BLOCKS, P_BLOCKS+ENC_BLOCKS): encoder role — the PROVEN R7 body
//   (118us standalone; spills ~67MB scratch but that traffic overlaps
//   ppart's atomic stalls here). One thread per node, uniform s_load
//   weights, t4-blocked.
// ---------------------------------------------------------------------------
__global__ __launch_bounds__(256, 1) void k_part_enc(
        const int*   __restrict__ ei,
        int*         __restrict__ gcur,      // stride-32 cursors, pre-zeroed
        unsigned int* __restrict__ ebuf,     // NBUCK * SORT_CAP
        const float* __restrict__ xl,
        const int*   __restrict__ batch,
        const float* __restrict__ xg,   const float* __restrict__ Wg,
        const float* __restrict__ bg,
        const float* __restrict__ Wl,   const float* __restrict__ bl,
        const float* __restrict__ Wmix, const float* __restrict__ bmix,
        const float* __restrict__ Wmsg, const float* __restrict__ bmsg,
        const float* __restrict__ Wself,const float* __restrict__ bself,
        ushort_t* __restrict__ mb, float* __restrict__ s) {
    __shared__ int cnt[NBUCK];
    __shared__ int basex[NBUCK];
    int tid = threadIdx.x;

    if (blockIdx.x < P_BLOCKS) {
        // ================= partition role (blocks 0..255, dispatch FIRST) ==
        int blk = blockIdx.x;
        for (int i = tid; i < NBUCK; i += 256) cnt[i] = 0;
        __syncthreads();

        int e0 = blk * EPB, e1 = e0 + EPB;
        for (int e = e0 + tid; e < e1; e += 256)
            atomicAdd(&cnt[ei[N_EDGES + e] >> 8], 1);
        __syncthreads();

        for (int i = tid; i < NBUCK; i += 256) {
            int c = cnt[i];
            basex[i] = (c > 0) ? atomicAdd(&gcur[i * 32], c) : 0;
        }
        __syncthreads();

        for (int e = e0 + tid; e < e1; e += 256) {
            unsigned src = (unsigned)ei[e];           // < 2^18
            int dst = ei[N_EDGES + e];
            int bkt = dst >> 8;
            int pos = atomicAdd(&basex[bkt], 1);
            if (pos < SORT_CAP)                       // belt-and-suspenders
                ebuf[(size_t)bkt * SORT_CAP + pos] = (src << 8) | (unsigned)(dst & 255);
        }
        return;
    }

    // ================= encoder role (R7 proven body, verbatim) =============
    int n0 = (blockIdx.x - P_BLOCKS) * 256 + tid;
    bool valid = (n0 < N_NODES);
    int n = valid ? n0 : (N_NODES - 1);     // clamp: loads safe, writes guarded

    float xv[16];
    {
        const float4* p = (const float4*)(xl + (size_t)n * 16);
        float4 a = p[0], b = p[1], c = p[2], d = p[3];
        xv[0]=a.x; xv[1]=a.y; xv[2]=a.z; xv[3]=a.w;
        xv[4]=b.x; xv[5]=b.y; xv[6]=b.z; xv[7]=b.w;
        xv[8]=c.x; xv[9]=c.y; xv[10]=c.z; xv[11]=c.w;
        xv[12]=d.x; xv[13]=d.y; xv[14]=d.z; xv[15]=d.w;
    }
    float gvv[8];
    {
        int gb = batch[n];
        const float4* q = (const float4*)(xg + (size_t)gb * 8);
        float4 a = q[0], b = q[1];
        gvv[0]=a.x; gvv[1]=a.y; gvv[2]=a.z; gvv[3]=a.w;
        gvv[4]=b.x; gvv[5]=b.y; gvv[6]=b.z; gvv[7]=b.w;
    }

    float hl[32], hg[32], hi[32];
#pragma unroll
    for (int t4 = 0; t4 < 8; ++t4) {
        float4 al = ((const float4*)bl)[t4];
        float4 ag = ((const float4*)bg)[t4];
#pragma unroll
        for (int k = 0; k < 16; ++k) {
            float4 w = ((const float4*)(Wl + k * H))[t4];   // uniform -> s_load
            al.x = fmaf(xv[k], w.x, al.x); al.y = fmaf(xv[k], w.y, al.y);
            al.z = fmaf(xv[k], w.z, al.z); al.w = fmaf(xv[k], w.w, al.w);
        }
#pragma unroll
        for (int k = 0; k < 8; ++k) {
            float4 w = ((const float4*)(Wg + k * H))[t4];
            ag.x = fmaf(gvv[k], w.x, ag.x); ag.y = fmaf(gvv[k], w.y, ag.y);
            ag.z = fmaf(gvv[k], w.z, ag.z); ag.w = fmaf(gvv[k], w.w, ag.w);
        }
        hl[t4*4+0] = fmaxf(al.x, 0.f); hl[t4*4+1] = fmaxf(al.y, 0.f);
        hl[t4*4+2] = fmaxf(al.z, 0.f); hl[t4*4+3] = fmaxf(al.w, 0.f);
        hg[t4*4+0] = fmaxf(ag.x, 0.f); hg[t4*4+1] = fmaxf(ag.y, 0.f);
        hg[t4*4+2] = fmaxf(ag.z, 0.f); hg[t4*4+3] = fmaxf(ag.w, 0.f);
    }
#pragma unroll
    for (int k = 0; k < 32; ++k) hi[k] = hl[k] * hg[k];

    float h0[32];
#pragma unroll
    for (int t4 = 0; t4 < 8; ++t4) {
        float4 acc = ((const float4*)bmix)[t4];
#pragma unroll
        for (int k = 0; k < 32; ++k) {
            float4 w = ((const float4*)(Wmix + k * H))[t4];
            acc.x = fmaf(hl[k], w.x, acc.x); acc.y = fmaf(hl[k], w.y, acc.y);
            acc.z = fmaf(hl[k], w.z, acc.z); acc.w = fmaf(hl[k], w.w, acc.w);
        }
#pragma unroll
        for (int k = 0; k < 32; ++k) {
            float4 w = ((const float4*)(Wmix + (32 + k) * H))[t4];
            acc.x = fmaf(hg[k], w.x, acc.x); acc.y = fmaf(hg[k], w.y, acc.y);
            acc.z = fmaf(hg[k], w.z, acc.z); acc.w = fmaf(hg[k], w.w, acc.w);
        }
#pragma unroll
        for (int k = 0; k < 32; ++k) {
            float4 w = ((const float4*)(Wmix + (64 + k) * H))[t4];
            acc.x = fmaf(hi[k], w.x, acc.x); acc.y = fmaf(hi[k], w.y, acc.y);
            acc.z = fmaf(hi[k], w.z, acc.z); acc.w = fmaf(hi[k], w.w, acc.w);
        }
        h0[t4*4+0] = fmaxf(acc.x, 0.f); h0[t4*4+1] = fmaxf(acc.y, 0.f);
        h0[t4*4+2] = fmaxf(acc.z, 0.f); h0[t4*4+3] = fmaxf(acc.w, 0.f);
    }

#pragma unroll
    for (int t4 = 0; t4 < 8; ++t4) {
        float4 am = ((const float4*)bmsg)[t4];
        float4 as = ((const float4*)bself)[t4];
#pragma unroll
        for (int k = 0; k < 32; ++k) {
            float4 wm = ((const float4*)(Wmsg + k * H))[t4];
            float4 ws = ((const float4*)(Wself + k * H))[t4];
            am.x = fmaf(h0[k], wm.x, am.x); am.y = fmaf(h0[k], wm.y, am.y);
            am.z = fmaf(h0[k], wm.z, am.z); am.w = fmaf(h0[k], wm.w, am.w);
            as.x = fmaf(h0[k], ws.x, as.x); as.y = fmaf(h0[k], ws.y, as.y);
            as.z = fmaf(h0[k], ws.z, as.z); as.w = fmaf(h0[k], ws.w, as.w);
        }
        if (valid) {
            unsigned d0 = (unsigned)f32_to_bf16_rne(fmaxf(am.x, 0.f))
                        | ((unsigned)f32_to_bf16_rne(fmaxf(am.y, 0.f)) << 16);
            unsigned d1 = (unsigned)f32_to_bf16_rne(fmaxf(am.z, 0.f))
                        | ((unsigned)f32_to_bf16_rne(fmaxf(am.w, 0.f)) << 16);
            ((unsigned*)(mb + (size_t)n * H))[t4*2+0] = d0;
            ((unsigned*)(mb + (size_t)n * H))[t4*2+1] = d1;
            ((float4*)(s + (size_t)n * H))[t4] = as;
        }
    }
}

// ---------------------------------------------------------------------------
// K-bsort-aggr: FUSED counting-sort + aggregation + output head (proven
// 114us, R8/R11/R12). One block per bucket. SORT_CAP 8960 => LDS 38.9 KB;
// 2-barrier shfl wave scan; INT LDS-atomic sort (2 lane-atomics/edge);
// register-accumulated aggregation with dword gathers (2 bf16 cols/lane,
// 16 lanes/edge). Epilogue verified R1-R12.
// ---------------------------------------------------------------------------
__global__ __launch_bounds__(512, 8) void k_bsort_aggr(
        const int* __restrict__ gcur,        // per-bucket counts (stride 32)
        const unsigned int* __restrict__ ebuf,
        const ushort_t* __restrict__ mb, const float* __restrict__ s,
        const float* __restrict__ Wout, const float* __restrict__ bout,
        float* __restrict__ out) {
    __shared__ unsigned sorted[SORT_CAP];   // 35 KB
    __shared__ int cnt[BNODES];
    __shared__ int offx[BNODES + 1];        // exclusive offsets, offx[256]=size
    __shared__ int cur[BNODES];
    __shared__ int wsum[4];
    int tid = threadIdx.x, b = blockIdx.x;

    size_t base = (size_t)b * SORT_CAP;
    int sz = min(gcur[b * 32], SORT_CAP);

    if (tid < BNODES) cnt[tid] = 0;
    __syncthreads();

    // histogram: 1 int LDS lane-atomic per edge
    for (int j = tid; j < sz; j += 512)
        atomicAdd(&cnt[ebuf[base + j] & 255], 1);
    __syncthreads();

    // 2-barrier shfl scan over 256 counts
    {
        int lane = tid & 63, w = tid >> 6;
        int v = (tid < BNODES) ? cnt[tid] : 0;
#pragma unroll
        for (int d = 1; d < 64; d <<= 1) {
            int u = __shfl_up(v, d, 64);    // harmless for waves 4-7
            if (lane >= d) v += u;
        }
        if (tid < BNODES && lane == 63) wsum[w] = v;
        __syncthreads();
        if (tid < BNODES) {
            int add = 0;
#pragma unroll
            for (int i = 0; i < 3; ++i) add += (i < w) ? wsum[i] : 0;
            int inc = v + add;              // inclusive scan of cnt
            offx[tid + 1] = inc;
            cur[tid] = inc - cnt[tid];      // exclusive (scatter cursor)
            if (tid == 0) offx[0] = 0;
        }
        __syncthreads();
    }

    // scatter into sorted[]: 1 int LDS lane-atomic per edge
    for (int j = tid; j < sz; j += 512) {
        unsigned pk = ebuf[base + j];
        int pos = atomicAdd(&cur[pk & 255], 1);
        sorted[pos] = pk;
    }
    __syncthreads();

    // ---- fused aggregation + output head (register accumulation) ----
    const unsigned* mb32 = (const unsigned*)mb;
    int g = tid >> 4;          // 16-lane group id, 0..31
    int t = tid & 15;          // lane in group; owns columns {2t, 2t+1}

    for (int q = 0; q < 8; ++q) {
        int loc = (g << 3) + q;            // 32 groups x 8 nodes = 256
        int n = b * BNODES + loc;
        int rs = offx[loc];
        int re = offx[loc + 1];
        float a0 = 0.f, a1 = 0.f;

        for (int j = rs; j < re; j += 8) {
            unsigned pk[8], u[8];
#pragma unroll
            for (int k = 0; k < 8; ++k)
                pk[k] = sorted[min(j + k, re - 1)];       // broadcast LDS read
#pragma unroll
            for (int k = 0; k < 8; ++k)
                u[k] = mb32[(pk[k] >> 8) * 16u + (unsigned)t];  // 2 bf16 cols
#pragma unroll
            for (int k = 0; k < 8; ++k) {
                bool ok = (j + k < re);
                a0 += ok ? __uint_as_float(u[k] << 16)         : 0.f;
                a1 += ok ? __uint_as_float(u[k] & 0xffff0000u) : 0.f;
            }
        }

        if (n < N_NODES) {
            // self-loop message + self path, relu, output head
            unsigned u = mb32[(unsigned)n * 16u + (unsigned)t];
            float2 sv = *(const float2*)(s + (size_t)n * H + 2 * t);
            float h0 = fmaxf(a0 + __uint_as_float(u << 16)         + sv.x, 0.f);
            float h1 = fmaxf(a1 + __uint_as_float(u & 0xffff0000u) + sv.y, 0.f);
            float4 w = *(const float4*)(Wout + 4 * t);   // rows {2t,2t+1} of [32][2]
            float p0 = h0 * w.x + h1 * w.z;
            float p1 = h0 * w.y + h1 * w.w;
#pragma unroll
            for (int o = 8; o >= 1; o >>= 1) {
                p0 += __shfl_down(p0, o, 16);
                p1 += __shfl_down(p1, o, 16);
            }
            if (t == 0) {
                float2 o2;
                o2.x = p0 + bout[0];
                o2.y = p1 + bout[1];
                *(float2*)(out + (size_t)n * 2) = o2;
            }
        }
    }
}

// ---------------------------------------------------------------------------
extern "C" void kernel_launch(void* const* d_in, const int* in_sizes, int n_in,
                              void* d_out, int out_size, void* d_ws, size_t ws_size,
                              hipStream_t stream) {
    const float* xl    = (const float*)d_in[0];
    const float* xg    = (const float*)d_in[1];
    const int*   batch = (const int*)  d_in[2];
    const int*   ei    = (const int*)  d_in[3];
    const float* Wl    = (const float*)d_in[4];
    const float* bl    = (const float*)d_in[5];
    const float* Wg    = (const float*)d_in[6];
    const float* bg    = (const float*)d_in[7];
    const float* Wmix  = (const float*)d_in[8];
    const float* bmix  = (const float*)d_in[9];
    const float* Wmsg  = (const float*)d_in[10];
    const float* bmsg  = (const float*)d_in[11];
    const float* Wself = (const float*)d_in[12];
    const float* bself = (const float*)d_in[13];
    const float* Wout  = (const float*)d_in[14];
    const float* bout  = (const float*)d_in[15];
    float* out = (float*)d_out;

    // Workspace layout (66.5 MB total — proven available R6-R12):
    //   s    [N*32]           f32   25.6 MB
    //   mb   [N*32]           u16   12.8 MB
    //   gcur [NBUCK*32]       i32   100 KB  (128B-line-padded cursors)
    //   ebuf [NBUCK*SORT_CAP] u32   28.0 MB (fixed-cap bucket regions)
    float*    s    = (float*)d_ws;
    ushort_t* mb   = (ushort_t*)(s + (size_t)N_NODES * H);
    int*      gcur = (int*)(mb + (size_t)N_NODES * H);
    unsigned int* ebuf = (unsigned int*)(gcur + (size_t)NBUCK * 32);

    hipMemsetAsync(gcur, 0, (size_t)NBUCK * 32 * sizeof(int), stream);

    // Fused: ppart blocks FIRST (0..255), enc blocks after (256..1037).
    // All 1038 blocks co-resident (~8 blocks/CU capacity at 6.4KB LDS,
    // VGPR~52) -> enc VALU work fills ppart atomic-stall cycles.
    k_part_enc<<<P_BLOCKS + ENC_BLOCKS, 256, 0, stream>>>(
        ei, gcur, ebuf,
        xl, batch, xg, Wg, bg, Wl, bl, Wmix, bmix,
        Wmsg, bmsg, Wself, bself, mb, s);

    k_bsort_aggr<<<NBUCK, 512, 0, stream>>>(gcur, ebuf, mb, s, Wout, bout, out);
}